// Round 10
// baseline (105.659 us; speedup 1.0000x reference)
//
#include <hip/hip_runtime.h>
#include <hip/hip_bf16.h>

// Problem constants
#define B_      4
#define C_IN    64
#define H_      64
#define W_      64
#define OUT_CH  128
#define HP_     66          // padded height (halo = features(0))
#define CF      576         // K per tap: 9 features * 64 channels, cf = j*64 + c
#define WP_BYTES  (9 * OUT_CH * CF * 2)          // 1,327,104
#define F_BYTES   (B_ * HP_ * HP_ * CF * 2)      // 20,072,448
#define P_OFFSET  (WP_BYTES + F_BYTES)           // 21,399,552 (16B aligned)
// partials: 512 blocks x 16384 half (block-linear fragment layout) = 16,777,216 B

typedef __bf16 bf16x8 __attribute__((ext_vector_type(8)));
typedef float  f32x4  __attribute__((ext_vector_type(4)));
typedef _Float16 half4 __attribute__((ext_vector_type(4)));
typedef unsigned short ushort8 __attribute__((ext_vector_type(8)));

// silu + cubic B-spline bases (Cox-de Boor), identical semantics to passing rounds.
__device__ __forceinline__ void compute_features(float x, float f[9]) {
    f[0] = x / (1.0f + __expf(-x));
    float g[12];
#pragma unroll
    for (int i = 0; i < 12; ++i) g[i] = (float)(i - 3) * 0.4f - 1.0f;
    float bb[11];
#pragma unroll
    for (int i = 0; i < 11; ++i) bb[i] = (x >= g[i] && x < g[i + 1]) ? 1.0f : 0.0f;
#pragma unroll
    for (int i = 0; i < 10; ++i)
        bb[i] = (x - g[i]) * (1.0f / (g[i + 1] - g[i])) * bb[i]
              + (g[i + 2] - x) * (1.0f / (g[i + 2] - g[i + 1])) * bb[i + 1];
#pragma unroll
    for (int i = 0; i < 9; ++i)
        bb[i] = (x - g[i]) * (1.0f / (g[i + 2] - g[i])) * bb[i]
              + (g[i + 3] - x) * (1.0f / (g[i + 3] - g[i + 1])) * bb[i + 1];
#pragma unroll
    for (int i = 0; i < 8; ++i)
        bb[i] = (x - g[i]) * (1.0f / (g[i + 3] - g[i])) * bb[i]
              + (g[i + 4] - x) * (1.0f / (g[i + 4] - g[i + 1])) * bb[i + 1];
#pragma unroll
    for (int i = 0; i < 8; ++i) f[1 + i] = bb[i];
}

__device__ __forceinline__ ushort bf16bits(float v) {
    __hip_bfloat16 h = __float2bfloat16(v);
    return *reinterpret_cast<ushort*>(&h);
}

// Kernel 1 (merged): blocks 0..527 = features, blocks 528..851 = weight pack.
// R8 version (measured best): both parts store 16 B/lane.
__global__ __launch_bounds__(256) void prep_kernel(
        const float* __restrict__ x, __hip_bfloat16* __restrict__ F,
        const float* __restrict__ bw, const float* __restrict__ sw,
        const float* __restrict__ sc, __hip_bfloat16* __restrict__ Wp) {
    __shared__ float xs[64][33];
    int blk = blockIdx.x;
    int tid = threadIdx.x;

    if (blk >= 528) {                                   // ---- pack part ----
        int widx = ((blk - 528) * 256 + tid) * 8;       // 0..663544, step 8
        int tap  = widx / 73728;                        // 576*128
        int rem  = widx - tap * 73728;
        int o    = rem / 576;
        int s    = rem - o * 576;                       // j-slot*64 + c, 8-aligned
        int jj   = s >> 6;                              // 0 = base, 1..8 = spline j-1
        int c0v  = s & 63;
        ushort8 v;
#pragma unroll
        for (int e = 0; e < 8; ++e) {
            int c = c0v + e;
            int d = c * 9 + tap;                        // patch-dim index
            float val = (jj == 0)
                ? bw[o * 576 + d]
                : sw[(o * 576 + d) * 8 + (jj - 1)] * sc[o * 576 + d];
            v[e] = bf16bits(val);
        }
        *(ushort8*)((ushort*)Wp + widx) = v;            // fully coalesced b128
        return;
    }

    // ---- feat part: one (b, hp, half-row) per block ----
    int half = blk & 1;                 // 0: w in [0,32)  1: w in [32,64)
    int bh   = blk >> 1;
    int b  = bh / HP_;
    int hp = bh % HP_;
    int h  = hp - 1;

    bool interior_row = (h >= 0) && (h < H_);
    if (interior_row) {
        int wl = tid & 31;
        int cq = tid >> 5;              // 0..7
#pragma unroll
        for (int i = 0; i < 8; ++i) {
            int c = cq * 8 + i;
            xs[c][wl] = x[((b * C_IN + c) * H_ + h) * W_ + half * 32 + wl];
        }
    }
    __syncthreads();

    // thread owns (w2 = pixel-in-half, c8 = channel block of 8)
    int w2 = tid >> 3;                  // 0..31
    int c8 = tid & 7;                   // 0..7
    ushort* Frow = (ushort*)F + (size_t)((b * HP_ + hp) * HP_) * CF;

    float f0[9];
    compute_features(0.0f, f0);
    ushort8 v0[9];
#pragma unroll
    for (int j = 0; j < 9; ++j) {
        ushort bits = bf16bits(f0[j]);
#pragma unroll
        for (int i = 0; i < 8; ++i) v0[j][i] = bits;
    }

    if (!interior_row) {                // hp = 0 or 65: constant features
        for (int wp = half * 33 + w2; wp < half * 33 + 33; wp += 32) {
            ushort* dst = Frow + (size_t)wp * CF + c8 * 8;
#pragma unroll
            for (int j = 0; j < 9; ++j) *(ushort8*)(dst + j * 64) = v0[j];
        }
        return;
    }
    // wp halos (interior rows): w2==0 threads cover all c via c8
    if (w2 == 0) {
        int wph = half ? 65 : 0;
        ushort* dst = Frow + (size_t)wph * CF + c8 * 8;
#pragma unroll
        for (int j = 0; j < 9; ++j) *(ushort8*)(dst + j * 64) = v0[j];
    }
    // interior: 8 channels of one pixel -> 9 x b128 stores
    ushort8 v[9];
#pragma unroll
    for (int i = 0; i < 8; ++i) {
        float xv = xs[c8 * 8 + i][w2];   // 2-way bank alias, free
        float f[9];
        compute_features(xv, f);
#pragma unroll
        for (int j = 0; j < 9; ++j) v[j][i] = bf16bits(f[j]);
    }
    int wp = half * 32 + w2 + 1;
    ushort* dst = Frow + (size_t)wp * CF + c8 * 8;
#pragma unroll
    for (int j = 0; j < 9; ++j) *(ushort8*)(dst + j * 64) = v[j];
}

// Kernel 2: implicit-GEMM conv, 4-way K-split. EXACT R1/R8 core (measured best).
// ONLY change: epilogue stores partials BLOCK-LINEAR in fragment order —
// P[blk*16384 + ((mt*4+nt)*256 + tid)*4 + rr] as half4 (8 B/lane contiguous,
// 512 B/wave-inst dense) instead of 64 scattered 2-B stores into [o][pix].
// The reduce kernel decodes the fragment coordinates.
__global__ __launch_bounds__(256, 2) void gemm_kernel(
        const __hip_bfloat16* __restrict__ Fb, const __hip_bfloat16* __restrict__ Wpb,
        _Float16* __restrict__ P) {
    __shared__ __align__(16) ushort As[2][8192];   // pixels:  [pix 0..127][cf 0..63] swizzled
    __shared__ __align__(16) ushort Bs[2][8192];   // weights: [o 0..127][cf 0..63] swizzled

    const ushort* F  = (const ushort*)Fb;
    const ushort* Wp = (const ushort*)Wpb;

    int tid  = threadIdx.x;
    int lane = tid & 63;
    int w    = tid >> 6;
    int l15  = lane & 15;
    int lq   = lane >> 4;
    int wm = w & 1;                  // out_ch half
    int wn = w >> 1;                 // pixel half
    int srow = lane >> 3;            // 0..7 staging sub-row
    int sl7  = lane & 7;
    int c8s  = sl7 ^ srow;           // staged c8 for this lane (swizzle-inverse)

    int blk = blockIdx.x;
    int g   = blk >> 7;              // K-group 0..3
    int t   = blk & 127;
    int b   = t >> 5;
    int ho0 = (t & 31) << 1;
    int c0 = (g == 0) ? 0 : (21 + 20 * (g - 1));   // {0,21,41,61}
    int c1 = c0 + ((g == 0) ? 21 : 20);            // 81 chunks total (tap*9 + kc)

    f32x4 acc[4][4];
#pragma unroll
    for (int i = 0; i < 4; ++i)
#pragma unroll
        for (int j = 0; j < 4; ++j) acc[i][j] = (f32x4){0.f, 0.f, 0.f, 0.f};

    auto prefetch = [&](int ch, int buf) {
        int tap = ch / 9;
        int kc  = ch - tap * 9;
        int kh  = tap / 3;
        int kw  = tap - kh * 3;
#pragma unroll
        for (int rr = 0; rr < 4; ++rr) {
            int row = (rr * 4 + w) * 8 + srow;      // 0..127 (pix or o)
            // A: features, tap-shifted pixel
            int hp = ho0 + (row >> 6) + kh;
            int wp = (row & 63) + kw;
            const ushort* srcA = F + (size_t)((b * HP_ + hp) * HP_ + wp) * CF
                                   + kc * 64 + c8s * 8;
            __builtin_amdgcn_global_load_lds(
                (const __attribute__((address_space(1))) unsigned int*)srcA,
                (__attribute__((address_space(3))) unsigned int*)&As[buf][(rr * 4 + w) * 512],
                16, 0, 0);
            // B: weights
            const ushort* srcB = Wp + (size_t)(tap * OUT_CH + row) * CF
                                    + kc * 64 + c8s * 8;
            __builtin_amdgcn_global_load_lds(
                (const __attribute__((address_space(1))) unsigned int*)srcB,
                (__attribute__((address_space(3))) unsigned int*)&Bs[buf][(rr * 4 + w) * 512],
                16, 0, 0);
        }
    };

    int buf = 0;
    prefetch(c0, 0);                 //  8 loads in flight
    prefetch(c0 + 1, 1);             // 16 in flight
    for (int ch = c0; ch < c1; ++ch) {
        // buf's 8 loads are the oldest outstanding; keep next chunk's 8 flying.
        if (ch + 1 < c1) asm volatile("s_waitcnt vmcnt(8)\n\ts_barrier" ::: "memory");
        else             asm volatile("s_waitcnt vmcnt(0)\n\ts_barrier" ::: "memory");

        bf16x8 af[2][4], bq[2][4];
#pragma unroll
        for (int ks = 0; ks < 2; ++ks) {
#pragma unroll
            for (int mt = 0; mt < 4; ++mt) {
                int o  = wm * 64 + mt * 16 + l15;
                int sl = o * 8 + ((ks * 4 + lq) ^ (o & 7));
                af[ks][mt] = *(const bf16x8*)&Bs[buf][sl * 8];
            }
#pragma unroll
            for (int nt = 0; nt < 4; ++nt) {
                int p  = wn * 64 + nt * 16 + l15;
                int sl = p * 8 + ((ks * 4 + lq) ^ (p & 7));
                bq[ks][nt] = *(const bf16x8*)&As[buf][sl * 8];
            }
        }
        // my reads of buf complete -> safe for everyone to overwrite after barrier
        asm volatile("s_waitcnt lgkmcnt(0)\n\ts_barrier" ::: "memory");
        if (ch + 2 < c1) prefetch(ch + 2, buf);   // issue early: hides under MFMAs

        __builtin_amdgcn_s_setprio(1);
#pragma unroll
        for (int ks = 0; ks < 2; ++ks)
#pragma unroll
            for (int mt = 0; mt < 4; ++mt)
#pragma unroll
                for (int nt = 0; nt < 4; ++nt)
                    acc[mt][nt] = __builtin_amdgcn_mfma_f32_16x16x32_bf16(
                        af[ks][mt], bq[ks][nt], acc[mt][nt], 0, 0, 0);
        __builtin_amdgcn_s_setprio(0);
        buf ^= 1;
    }

    // epilogue: block-linear fp16 partials, fully coalesced half4 stores.
    _Float16* Pg = P + (size_t)blk * 16384;
#pragma unroll
    for (int mt = 0; mt < 4; ++mt)
#pragma unroll
        for (int nt = 0; nt < 4; ++nt) {
            half4 v;
#pragma unroll
            for (int rr = 0; rr < 4; ++rr) v[rr] = (_Float16)acc[mt][nt][rr];
            *(half4*)&Pg[(size_t)(((mt * 4 + nt) * 256 + tid) * 4)] = v;
        }
}

// Kernel 3: reduce 4 fp16 partials (block-linear fragment layout) -> fp32 out.
// Reads dense half4 per g (same add order as before: ((g0+g1)+g2)+g3), decodes
// fragment coords, 4x4 in-register quad transpose (2x shfl_xor rounds), writes
// dense float4 of 4 consecutive pixels. Values bit-identical to old reduce.
__global__ __launch_bounds__(256) void reduce_kernel(
        const _Float16* __restrict__ P, float* __restrict__ out) {
    int j  = blockIdx.x * 256 + threadIdx.x;   // 0..524287
    int t  = j >> 12;                          // tile 0..127
    int qi = j & 4095;                         // quad within tile
    const size_t gs = (size_t)128 * 16384;     // halfs per K-group
    const _Float16* Pq = P + (size_t)t * 16384 + (size_t)qi * 4;
    half4 a0 = *(const half4*)(Pq);
    half4 a1 = *(const half4*)(Pq + gs);
    half4 a2 = *(const half4*)(Pq + 2 * gs);
    half4 a3 = *(const half4*)(Pq + 3 * gs);
    float v[4];
#pragma unroll
    for (int e = 0; e < 4; ++e)
        v[e] = (((float)a0[e] + (float)a1[e]) + (float)a2[e]) + (float)a3[e];

    // 4x4 transpose across the HW quad (lanes k=0..3 hold regs e=0..3):
    // target v_k[e] = orig v_e[k].
    int k = threadIdx.x & 3;
    float q0 = __shfl_xor(v[1], 1), q1 = __shfl_xor(v[0], 1),
          q2 = __shfl_xor(v[3], 1), q3 = __shfl_xor(v[2], 1);
    v[0] = (k & 1) ? q0 : v[0];
    v[1] = (k & 1) ? v[1] : q1;
    v[2] = (k & 1) ? q2 : v[2];
    v[3] = (k & 1) ? v[3] : q3;
    float p0 = __shfl_xor(v[2], 2), p1 = __shfl_xor(v[3], 2),
          p2 = __shfl_xor(v[0], 2), p3 = __shfl_xor(v[1], 2);
    v[0] = (k & 2) ? p0 : v[0];
    v[1] = (k & 2) ? p1 : v[1];
    v[2] = (k & 2) ? v[2] : p2;
    v[3] = (k & 2) ? v[3] : p3;

    // decode fragment coords (must mirror the gemm wave/fragment mapping)
    int tid_g = qi & 255, ntmt = qi >> 8;
    int mt = ntmt >> 2, nt = ntmt & 3;
    int lane = tid_g & 63, w = tid_g >> 6;
    int wm = w & 1, wn = w >> 1, l15 = lane & 15, lq = lane >> 4;
    int o    = wm * 64 + mt * 16 + lq * 4 + k;       // my row after transpose
    int pixb = wn * 64 + nt * 16 + (l15 & ~3);       // 4 consecutive pixels
    int b = t >> 5, ho0 = (t & 31) << 1;
    float4 r4 = make_float4(v[0], v[1], v[2], v[3]);
    *(float4*)&out[((size_t)(b * 128 + o) * 4096) + ho0 * 64 + pixb] = r4;
}

extern "C" void kernel_launch(void* const* d_in, const int* in_sizes, int n_in,
                              void* d_out, int out_size, void* d_ws, size_t ws_size,
                              hipStream_t stream) {
    const float* x  = (const float*)d_in[0];   // (4,64,64,64)
    const float* bw = (const float*)d_in[1];   // (128,576)
    const float* sw = (const float*)d_in[2];   // (128,576,8)
    const float* sc = (const float*)d_in[3];   // (128,576)
    float* out = (float*)d_out;                // (4,128,64,64) fp32

    __hip_bfloat16* Wp = (__hip_bfloat16*)d_ws;
    __hip_bfloat16* F  = (__hip_bfloat16*)((char*)d_ws + WP_BYTES);
    _Float16*       P  = (_Float16*)((char*)d_ws + P_OFFSET);

    prep_kernel<<<528 + 324, 256, 0, stream>>>(x, F, bw, sw, sc, Wp);
    gemm_kernel<<<512, 256, 0, stream>>>(F, Wp, P);
    reduce_kernel<<<2048, 256, 0, stream>>>(P, out);
}

// Round 11
// 101.153 us; speedup vs baseline: 1.0445x; 1.0445x over previous
//
#include <hip/hip_runtime.h>
#include <hip/hip_bf16.h>

// Problem constants
#define B_      4
#define C_IN    64
#define H_      64
#define W_      64
#define OUT_CH  128
#define HP_     66          // padded height (halo = features(0))
#define CF      576         // K per tap: 9 features * 64 channels, cf = j*64 + c
#define WP_BYTES  (9 * OUT_CH * CF * 2)          // 1,327,104
#define F_BYTES   (B_ * HP_ * HP_ * CF * 2)      // 20,072,448
#define P_OFFSET  (WP_BYTES + F_BYTES)           // 21,399,552 (16B aligned)
// partials: 4 K-groups x (4 b x 128 o x 4096 pix) fp16 = 16,777,216 B

typedef __bf16 bf16x8 __attribute__((ext_vector_type(8)));
typedef float  f32x4  __attribute__((ext_vector_type(4)));
typedef _Float16 half8 __attribute__((ext_vector_type(8)));
typedef unsigned short ushort8 __attribute__((ext_vector_type(8)));

// silu + cubic B-spline bases (Cox-de Boor), identical semantics to passing rounds.
__device__ __forceinline__ void compute_features(float x, float f[9]) {
    f[0] = x / (1.0f + __expf(-x));
    float g[12];
#pragma unroll
    for (int i = 0; i < 12; ++i) g[i] = (float)(i - 3) * 0.4f - 1.0f;
    float bb[11];
#pragma unroll
    for (int i = 0; i < 11; ++i) bb[i] = (x >= g[i] && x < g[i + 1]) ? 1.0f : 0.0f;
#pragma unroll
    for (int i = 0; i < 10; ++i)
        bb[i] = (x - g[i]) * (1.0f / (g[i + 1] - g[i])) * bb[i]
              + (g[i + 2] - x) * (1.0f / (g[i + 2] - g[i + 1])) * bb[i + 1];
#pragma unroll
    for (int i = 0; i < 9; ++i)
        bb[i] = (x - g[i]) * (1.0f / (g[i + 2] - g[i])) * bb[i]
              + (g[i + 3] - x) * (1.0f / (g[i + 3] - g[i + 1])) * bb[i + 1];
#pragma unroll
    for (int i = 0; i < 8; ++i)
        bb[i] = (x - g[i]) * (1.0f / (g[i + 3] - g[i])) * bb[i]
              + (g[i + 4] - x) * (1.0f / (g[i + 4] - g[i + 1])) * bb[i + 1];
#pragma unroll
    for (int i = 0; i < 8; ++i) f[1 + i] = bb[i];
}

__device__ __forceinline__ ushort bf16bits(float v) {
    __hip_bfloat16 h = __float2bfloat16(v);
    return *reinterpret_cast<ushort*>(&h);
}

// Kernel 1 (merged): blocks 0..527 = features, blocks 528..851 = weight pack.
// R8 version (measured best): both parts store 16 B/lane.
__global__ __launch_bounds__(256) void prep_kernel(
        const float* __restrict__ x, __hip_bfloat16* __restrict__ F,
        const float* __restrict__ bw, const float* __restrict__ sw,
        const float* __restrict__ sc, __hip_bfloat16* __restrict__ Wp) {
    __shared__ float xs[64][33];
    int blk = blockIdx.x;
    int tid = threadIdx.x;

    if (blk >= 528) {                                   // ---- pack part ----
        int widx = ((blk - 528) * 256 + tid) * 8;       // 0..663544, step 8
        int tap  = widx / 73728;                        // 576*128
        int rem  = widx - tap * 73728;
        int o    = rem / 576;
        int s    = rem - o * 576;                       // j-slot*64 + c, 8-aligned
        int jj   = s >> 6;                              // 0 = base, 1..8 = spline j-1
        int c0v  = s & 63;
        ushort8 v;
#pragma unroll
        for (int e = 0; e < 8; ++e) {
            int c = c0v + e;
            int d = c * 9 + tap;                        // patch-dim index
            float val = (jj == 0)
                ? bw[o * 576 + d]
                : sw[(o * 576 + d) * 8 + (jj - 1)] * sc[o * 576 + d];
            v[e] = bf16bits(val);
        }
        *(ushort8*)((ushort*)Wp + widx) = v;            // fully coalesced b128
        return;
    }

    // ---- feat part: one (b, hp, half-row) per block ----
    int half = blk & 1;                 // 0: w in [0,32)  1: w in [32,64)
    int bh   = blk >> 1;
    int b  = bh / HP_;
    int hp = bh % HP_;
    int h  = hp - 1;

    bool interior_row = (h >= 0) && (h < H_);
    if (interior_row) {
        int wl = tid & 31;
        int cq = tid >> 5;              // 0..7
#pragma unroll
        for (int i = 0; i < 8; ++i) {
            int c = cq * 8 + i;
            xs[c][wl] = x[((b * C_IN + c) * H_ + h) * W_ + half * 32 + wl];
        }
    }
    __syncthreads();

    // thread owns (w2 = pixel-in-half, c8 = channel block of 8)
    int w2 = tid >> 3;                  // 0..31
    int c8 = tid & 7;                   // 0..7
    ushort* Frow = (ushort*)F + (size_t)((b * HP_ + hp) * HP_) * CF;

    float f0[9];
    compute_features(0.0f, f0);
    ushort8 v0[9];
#pragma unroll
    for (int j = 0; j < 9; ++j) {
        ushort bits = bf16bits(f0[j]);
#pragma unroll
        for (int i = 0; i < 8; ++i) v0[j][i] = bits;
    }

    if (!interior_row) {                // hp = 0 or 65: constant features
        for (int wp = half * 33 + w2; wp < half * 33 + 33; wp += 32) {
            ushort* dst = Frow + (size_t)wp * CF + c8 * 8;
#pragma unroll
            for (int j = 0; j < 9; ++j) *(ushort8*)(dst + j * 64) = v0[j];
        }
        return;
    }
    // wp halos (interior rows): w2==0 threads cover all c via c8
    if (w2 == 0) {
        int wph = half ? 65 : 0;
        ushort* dst = Frow + (size_t)wph * CF + c8 * 8;
#pragma unroll
        for (int j = 0; j < 9; ++j) *(ushort8*)(dst + j * 64) = v0[j];
    }
    // interior: 8 channels of one pixel -> 9 x b128 stores
    ushort8 v[9];
#pragma unroll
    for (int i = 0; i < 8; ++i) {
        float xv = xs[c8 * 8 + i][w2];   // 2-way bank alias, free
        float f[9];
        compute_features(xv, f);
#pragma unroll
        for (int j = 0; j < 9; ++j) v[j][i] = bf16bits(f[j]);
    }
    int wp = half * 32 + w2 + 1;
    ushort* dst = Frow + (size_t)wp * CF + c8 * 8;
#pragma unroll
    for (int j = 0; j < 9; ++j) *(ushort8*)(dst + j * 64) = v[j];
}

// Kernel 2: implicit-GEMM conv, 4-way K-split. EXACT R1/R8 core (measured best:
// default block order, dual LDS staging, double-buffer, counted vmcnt(8),
// mid-loop lgkm0+barrier, early prefetch, setprio).
__global__ __launch_bounds__(256, 2) void gemm_kernel(
        const __hip_bfloat16* __restrict__ Fb, const __hip_bfloat16* __restrict__ Wpb,
        _Float16* __restrict__ P) {
    __shared__ __align__(16) ushort As[2][8192];   // pixels:  [pix 0..127][cf 0..63] swizzled
    __shared__ __align__(16) ushort Bs[2][8192];   // weights: [o 0..127][cf 0..63] swizzled

    const ushort* F  = (const ushort*)Fb;
    const ushort* Wp = (const ushort*)Wpb;

    int tid  = threadIdx.x;
    int lane = tid & 63;
    int w    = tid >> 6;
    int l15  = lane & 15;
    int lq   = lane >> 4;
    int wm = w & 1;                  // out_ch half
    int wn = w >> 1;                 // pixel half
    int srow = lane >> 3;            // 0..7 staging sub-row
    int sl7  = lane & 7;
    int c8s  = sl7 ^ srow;           // staged c8 for this lane (swizzle-inverse)

    int blk = blockIdx.x;
    int g   = blk >> 7;              // K-group 0..3
    int t   = blk & 127;
    int b   = t >> 5;
    int ho0 = (t & 31) << 1;
    int c0 = (g == 0) ? 0 : (21 + 20 * (g - 1));   // {0,21,41,61}
    int c1 = c0 + ((g == 0) ? 21 : 20);            // 81 chunks total (tap*9 + kc)

    f32x4 acc[4][4];
#pragma unroll
    for (int i = 0; i < 4; ++i)
#pragma unroll
        for (int j = 0; j < 4; ++j) acc[i][j] = (f32x4){0.f, 0.f, 0.f, 0.f};

    auto prefetch = [&](int ch, int buf) {
        int tap = ch / 9;
        int kc  = ch - tap * 9;
        int kh  = tap / 3;
        int kw  = tap - kh * 3;
#pragma unroll
        for (int rr = 0; rr < 4; ++rr) {
            int row = (rr * 4 + w) * 8 + srow;      // 0..127 (pix or o)
            // A: features, tap-shifted pixel
            int hp = ho0 + (row >> 6) + kh;
            int wp = (row & 63) + kw;
            const ushort* srcA = F + (size_t)((b * HP_ + hp) * HP_ + wp) * CF
                                   + kc * 64 + c8s * 8;
            __builtin_amdgcn_global_load_lds(
                (const __attribute__((address_space(1))) unsigned int*)srcA,
                (__attribute__((address_space(3))) unsigned int*)&As[buf][(rr * 4 + w) * 512],
                16, 0, 0);
            // B: weights
            const ushort* srcB = Wp + (size_t)(tap * OUT_CH + row) * CF
                                    + kc * 64 + c8s * 8;
            __builtin_amdgcn_global_load_lds(
                (const __attribute__((address_space(1))) unsigned int*)srcB,
                (__attribute__((address_space(3))) unsigned int*)&Bs[buf][(rr * 4 + w) * 512],
                16, 0, 0);
        }
    };

    int buf = 0;
    prefetch(c0, 0);                 //  8 loads in flight
    prefetch(c0 + 1, 1);             // 16 in flight
    for (int ch = c0; ch < c1; ++ch) {
        // buf's 8 loads are the oldest outstanding; keep next chunk's 8 flying.
        if (ch + 1 < c1) asm volatile("s_waitcnt vmcnt(8)\n\ts_barrier" ::: "memory");
        else             asm volatile("s_waitcnt vmcnt(0)\n\ts_barrier" ::: "memory");

        bf16x8 af[2][4], bq[2][4];
#pragma unroll
        for (int ks = 0; ks < 2; ++ks) {
#pragma unroll
            for (int mt = 0; mt < 4; ++mt) {
                int o  = wm * 64 + mt * 16 + l15;
                int sl = o * 8 + ((ks * 4 + lq) ^ (o & 7));
                af[ks][mt] = *(const bf16x8*)&Bs[buf][sl * 8];
            }
#pragma unroll
            for (int nt = 0; nt < 4; ++nt) {
                int p  = wn * 64 + nt * 16 + l15;
                int sl = p * 8 + ((ks * 4 + lq) ^ (p & 7));
                bq[ks][nt] = *(const bf16x8*)&As[buf][sl * 8];
            }
        }
        // my reads of buf complete -> safe for everyone to overwrite after barrier
        asm volatile("s_waitcnt lgkmcnt(0)\n\ts_barrier" ::: "memory");
        if (ch + 2 < c1) prefetch(ch + 2, buf);   // issue early: hides under MFMAs

        __builtin_amdgcn_s_setprio(1);
#pragma unroll
        for (int ks = 0; ks < 2; ++ks)
#pragma unroll
            for (int mt = 0; mt < 4; ++mt)
#pragma unroll
                for (int nt = 0; nt < 4; ++nt)
                    acc[mt][nt] = __builtin_amdgcn_mfma_f32_16x16x32_bf16(
                        af[ks][mt], bq[ks][nt], acc[mt][nt], 0, 0, 0);
        __builtin_amdgcn_s_setprio(0);
        buf ^= 1;
    }

    // epilogue: fp16 partials. P[((g*4+b)*128 + o)*4096 + ho0*64 + pix]
    _Float16* Pg = P + ((size_t)(g * 4 + b) * OUT_CH) * 4096 + ho0 * 64;
#pragma unroll
    for (int mt = 0; mt < 4; ++mt) {
        int o = wm * 64 + mt * 16 + lq * 4;
#pragma unroll
        for (int nt = 0; nt < 4; ++nt) {
            int pix = wn * 64 + nt * 16 + l15;
            _Float16* dst = Pg + (size_t)o * 4096 + pix;
#pragma unroll
            for (int rr = 0; rr < 4; ++rr)
                dst[(size_t)rr * 4096] = (_Float16)acc[mt][nt][rr];
        }
    }
}

// Kernel 3: reduce 4 fp16 partials -> fp32 out. Fully coalesced half8/float4.
__global__ __launch_bounds__(256) void reduce_kernel(
        const half8* __restrict__ P, float4* __restrict__ out) {
    const int GS = 262144;                    // half8 per K-group (4*128*4096/8)
    int i = blockIdx.x * 256 + threadIdx.x;   // 0..262143
    half8 a = P[i], bb = P[GS + i], c = P[2 * GS + i], d = P[3 * GS + i];
    float4 o0, o1;
#pragma unroll
    for (int j = 0; j < 4; ++j)
        ((float*)&o0)[j] = (float)a[j] + (float)bb[j] + (float)c[j] + (float)d[j];
#pragma unroll
    for (int j = 0; j < 4; ++j)
        ((float*)&o1)[j] = (float)a[4 + j] + (float)bb[4 + j] + (float)c[4 + j] + (float)d[4 + j];
    out[i * 2]     = o0;
    out[i * 2 + 1] = o1;
}

extern "C" void kernel_launch(void* const* d_in, const int* in_sizes, int n_in,
                              void* d_out, int out_size, void* d_ws, size_t ws_size,
                              hipStream_t stream) {
    const float* x  = (const float*)d_in[0];   // (4,64,64,64)
    const float* bw = (const float*)d_in[1];   // (128,576)
    const float* sw = (const float*)d_in[2];   // (128,576,8)
    const float* sc = (const float*)d_in[3];   // (128,576)
    float* out = (float*)d_out;                // (4,128,64,64) fp32

    __hip_bfloat16* Wp = (__hip_bfloat16*)d_ws;
    __hip_bfloat16* F  = (__hip_bfloat16*)((char*)d_ws + WP_BYTES);
    _Float16*       P  = (_Float16*)((char*)d_ws + P_OFFSET);

    prep_kernel<<<528 + 324, 256, 0, stream>>>(x, F, bw, sw, sc, Wp);
    gemm_kernel<<<512, 256, 0, stream>>>(F, Wp, P);
    reduce_kernel<<<1024, 256, 0, stream>>>((const half8*)P, (float4*)out);
}